// Round 1
// baseline (323.719 us; speedup 1.0000x reference)
//
#include <hip/hip_runtime.h>

typedef unsigned short u16;
typedef unsigned int   u32;
typedef __attribute__((ext_vector_type(4))) float f32x4;
typedef __attribute__((ext_vector_type(8))) __bf16 bf16x8;
typedef __attribute__((ext_vector_type(8))) u16  u16x8;
typedef __attribute__((ext_vector_type(4))) u16  u16x4;

#define HDIM 1024
#define SEQ  2048
#define NB   2
#define MROWS 4096   /* B*S */

__device__ __forceinline__ u16 f2bf(float f) {
  u32 u = __float_as_uint(f);
  u32 r = u + 0x7FFFu + ((u >> 16) & 1u);
  return (u16)(r >> 16);
}

__device__ __forceinline__ void gload_lds16(const void* gp, void* lp) {
  __builtin_amdgcn_global_load_lds(
      (const __attribute__((address_space(1))) void*)gp,
      (__attribute__((address_space(3))) void*)lp, 16, 0, 0);
}

/* ---- weights fp32 [K][N] -> bf16 transposed [N][K], 4 matrices ---- */
__global__ void wt_bf16_kernel(const float* __restrict__ w0, const float* __restrict__ w1,
                               const float* __restrict__ w2, const float* __restrict__ w3,
                               u16* __restrict__ out) {
  const float* W = (blockIdx.z == 0) ? w0 : (blockIdx.z == 1) ? w1 : (blockIdx.z == 2) ? w2 : w3;
  u16* Wt = out + (size_t)blockIdx.z * HDIM * HDIM;
  __shared__ float t[32][33];
  const int k0 = blockIdx.x * 32, n0 = blockIdx.y * 32;
  const int tx = threadIdx.x, ty = threadIdx.y;
#pragma unroll
  for (int j = 0; j < 32; j += 8)
    t[ty + j][tx] = W[(size_t)(k0 + ty + j) * HDIM + n0 + tx];
  __syncthreads();
#pragma unroll
  for (int j = 0; j < 32; j += 8)
    Wt[(size_t)(n0 + ty + j) * HDIM + k0 + tx] = f2bf(t[tx][ty + j]);
}

/* ---- fp32 -> bf16, 4 elems/thread ---- */
__global__ void cvt_bf16_kernel(const float* __restrict__ in, u16* __restrict__ out) {
  const size_t i = (size_t)blockIdx.x * 256 + threadIdx.x;
  f32x4 v = *(const f32x4*)(in + i * 4);
  u16x4 o;
#pragma unroll
  for (int e = 0; e < 4; ++e) o[e] = f2bf(v[e]);
  *(u16x4*)(out + i * 4) = o;
}

/* ---- tiny topic GEMV: out[b][n] = act(in[b]·W[:,n] + bias[n]) ---- */
__global__ void topic_mm_kernel(const float* __restrict__ in, const float* __restrict__ W,
                                const float* __restrict__ bias, float* __restrict__ out,
                                int sigmoid_mode) {
  const int b = blockIdx.y;
  const int n = blockIdx.x * 64 + (threadIdx.x & 63);
  const int kc = threadIdx.x >> 6;
  const float* inb = in + b * HDIM;
  float s = 0.f;
  for (int k = kc * 256; k < kc * 256 + 256; ++k)
    s += inb[k] * W[(size_t)k * HDIM + n];
  __shared__ float red[256];
  red[threadIdx.x] = s;
  __syncthreads();
  if (threadIdx.x < 64) {
    float t = red[threadIdx.x] + red[threadIdx.x + 64] + red[threadIdx.x + 128] +
              red[threadIdx.x + 192] + bias[n];
    out[b * HDIM + n] = sigmoid_mode ? (1.f / (1.f + __expf(-t))) : t;
  }
}

/* ---- 128x128 bf16 MFMA GEMM.  A [M][1024] bf16, Wt [N][K] bf16.
   MODE 0: z in {0,1,2} = q,k,v; bias per z; z==1 multiplies gate; bf16 out.
   MODE 1: bias + residual, fp32 out. ---- */
template <int MODE>
__global__ __launch_bounds__(256, 2)
void gemm_kernel(const u16* __restrict__ A, const u16* __restrict__ Wt,
                 const float* __restrict__ b0, const float* __restrict__ b1,
                 const float* __restrict__ b2, const float* __restrict__ gate,
                 const float* __restrict__ resid,
                 u16* __restrict__ outb, float* __restrict__ outf) {
  const int n0 = blockIdx.x * 128;
  const int m0 = blockIdx.y * 128;
  const int z = blockIdx.z;
  const u16* W = Wt + (size_t)z * (HDIM * HDIM);
  const float* bias = (MODE == 0) ? (z == 0 ? b0 : (z == 1 ? b1 : b2)) : b0;

  __shared__ __align__(16) u16 Alds[128 * 64];
  __shared__ __align__(16) u16 Blds[128 * 64];

  const int tid = threadIdx.x;
  const int lane = tid & 63;
  const int w = tid >> 6;
  const int wm = w >> 1, wn = w & 1;
  const int srow = tid >> 3, sslot = tid & 7;

  f32x4 acc[4][4] = {};

  for (int k0 = 0; k0 < HDIM; k0 += 64) {
    __syncthreads();
#pragma unroll
    for (int j = 0; j < 4; ++j) {
      const int row = j * 32 + srow;
      const int gs = (sslot ^ (row & 7)) * 8;   /* inverse-swizzled global source */
      gload_lds16(A + (size_t)(m0 + row) * HDIM + k0 + gs, Alds + j * 2048 + w * 512);
      gload_lds16(W + (size_t)(n0 + row) * HDIM + k0 + gs, Blds + j * 2048 + w * 512);
    }
    __syncthreads();
#pragma unroll
    for (int kk = 0; kk < 2; ++kk) {
      const int slot = ((((kk << 2) + (lane >> 4)) ^ (lane & 7)) << 3); /* swizzled read */
      bf16x8 af[4], bfr[4];
#pragma unroll
      for (int i = 0; i < 4; ++i) {
        af[i]  = *(const bf16x8*)(&Alds[(wm * 64 + i * 16 + (lane & 15)) * 64 + slot]);
        bfr[i] = *(const bf16x8*)(&Blds[(wn * 64 + i * 16 + (lane & 15)) * 64 + slot]);
      }
#pragma unroll
      for (int i = 0; i < 4; ++i)
#pragma unroll
        for (int jn = 0; jn < 4; ++jn)
          acc[i][jn] = __builtin_amdgcn_mfma_f32_16x16x32_bf16(af[i], bfr[jn], acc[i][jn], 0, 0, 0);
    }
  }

  const int rbase = (lane >> 4) << 2;
#pragma unroll
  for (int i = 0; i < 4; ++i) {
#pragma unroll
    for (int jn = 0; jn < 4; ++jn) {
      const int n = n0 + wn * 64 + jn * 16 + (lane & 15);
      const float bv = bias[n];
#pragma unroll
      for (int r = 0; r < 4; ++r) {
        const int m = m0 + wm * 64 + i * 16 + rbase + r;
        float v = acc[i][jn][r] + bv;
        if (MODE == 0) {
          if (z == 1) v *= gate[(m >> 11) * HDIM + n];
          outb[(size_t)z * MROWS * HDIM + (size_t)m * HDIM + n] = f2bf(v);
        } else {
          v += resid[(size_t)m * HDIM + n];
          outf[(size_t)m * HDIM + n] = v;
        }
      }
    }
  }
}

/* ---- flash attention: 128 q-rows/block (4 waves x 32), 64-kv tiles ---- */
__global__ __launch_bounds__(256, 2)
void attn_kernel(const u16* __restrict__ Q, const u16* __restrict__ K,
                 const u16* __restrict__ V, const float* __restrict__ mask,
                 u16* __restrict__ O) {
  const int q0 = blockIdx.x * 128;
  const int h = blockIdx.y;
  const int b = blockIdx.z;
  const size_t base = ((size_t)b * SEQ) * HDIM + h * 64;
  const int tid = threadIdx.x, lane = tid & 63, w = tid >> 6;
  const int srow = tid >> 3, sslot = tid & 7;

  __shared__ __align__(16) u16 Qs[128 * 64];
  __shared__ __align__(16) u16 Ks[64 * 64];
  __shared__ __align__(16) u16 Vt[64 * 64];     /* [d][kv], swizzled */
  __shared__ __align__(16) u16 Ps[4][32 * 64];  /* per-wave P tile */

#pragma unroll
  for (int j = 0; j < 4; ++j) {
    const int row = j * 32 + srow;
    const int gs = (sslot ^ (row & 7)) * 8;
    gload_lds16(Q + base + (size_t)(q0 + row) * HDIM + gs, Qs + j * 2048 + w * 512);
  }

  float m_run[2][4], l_run[2][4];
  f32x4 acc[2][4] = {};
#pragma unroll
  for (int qi = 0; qi < 2; ++qi)
#pragma unroll
    for (int r = 0; r < 4; ++r) { m_run[qi][r] = -1e30f; l_run[qi][r] = 0.f; }

  for (int kv0 = 0; kv0 < SEQ; kv0 += 64) {
    __syncthreads();                       /* prev PV done; LDS reusable */
#pragma unroll
    for (int j = 0; j < 2; ++j) {
      const int row = j * 32 + srow;
      const int gs = (sslot ^ (row & 7)) * 8;
      gload_lds16(K + base + (size_t)(kv0 + row) * HDIM + gs, Ks + j * 2048 + w * 512);
    }
#pragma unroll
    for (int j = 0; j < 2; ++j) {          /* V -> Vt transposed (reg-staged) */
      const int kr = j * 32 + srow;
      u16x8 vv = *(const u16x8*)(V + base + (size_t)(kv0 + kr) * HDIM + sslot * 8);
#pragma unroll
      for (int e = 0; e < 8; ++e) {
        const int d = sslot * 8 + e;
        Vt[d * 64 + ((((kr >> 3) ^ (d & 7) ^ ((d >> 3) & 7))) << 3) + (kr & 7)] = vv[e];
      }
    }
    __syncthreads();                       /* staging visible */

    /* QK^T */
    f32x4 sf[2][4] = {};
#pragma unroll
    for (int kk = 0; kk < 2; ++kk) {
      const int slot = ((((kk << 2) + (lane >> 4)) ^ (lane & 7)) << 3);
      bf16x8 qf[2], kf[4];
#pragma unroll
      for (int qi = 0; qi < 2; ++qi)
        qf[qi] = *(const bf16x8*)(&Qs[(w * 32 + qi * 16 + (lane & 15)) * 64 + slot]);
#pragma unroll
      for (int kj = 0; kj < 4; ++kj)
        kf[kj] = *(const bf16x8*)(&Ks[(kj * 16 + (lane & 15)) * 64 + slot]);
#pragma unroll
      for (int qi = 0; qi < 2; ++qi)
#pragma unroll
        for (int kj = 0; kj < 4; ++kj)
          sf[qi][kj] = __builtin_amdgcn_mfma_f32_16x16x32_bf16(qf[qi], kf[kj], sf[qi][kj], 0, 0, 0);
    }

    /* scale + additive mask */
#pragma unroll
    for (int kj = 0; kj < 4; ++kj) {
      const float mk = mask[(size_t)b * SEQ + kv0 + kj * 16 + (lane & 15)];
#pragma unroll
      for (int qi = 0; qi < 2; ++qi)
#pragma unroll
        for (int r = 0; r < 4; ++r)
          sf[qi][kj][r] = sf[qi][kj][r] * 0.125f + mk;
    }

    /* online softmax (wave-parallel, 16-lane row groups) + P write */
#pragma unroll
    for (int qi = 0; qi < 2; ++qi) {
#pragma unroll
      for (int r = 0; r < 4; ++r) {
        float mx = fmaxf(fmaxf(sf[qi][0][r], sf[qi][1][r]), fmaxf(sf[qi][2][r], sf[qi][3][r]));
#pragma unroll
        for (int o = 1; o < 16; o <<= 1) mx = fmaxf(mx, __shfl_xor(mx, o));
        const float mnew = fmaxf(m_run[qi][r], mx);
        const float corr = __expf(m_run[qi][r] - mnew);
        float rs = 0.f;
#pragma unroll
        for (int kj = 0; kj < 4; ++kj) {
          const float p = __expf(sf[qi][kj][r] - mnew);
          sf[qi][kj][r] = p;
          rs += p;
        }
#pragma unroll
        for (int o = 1; o < 16; o <<= 1) rs += __shfl_xor(rs, o);
        m_run[qi][r] = mnew;
        l_run[qi][r] = l_run[qi][r] * corr + rs;
#pragma unroll
        for (int dj = 0; dj < 4; ++dj) acc[qi][dj][r] *= corr;
      }
#pragma unroll
      for (int kj = 0; kj < 4; ++kj)
#pragma unroll
        for (int r = 0; r < 4; ++r) {
          const int qrow = qi * 16 + ((lane >> 4) << 2) + r;
          const int c = kj * 16 + (lane & 15);
          Ps[w][qrow * 64 + (((c >> 3) ^ (qrow & 7)) << 3) + (c & 7)] = f2bf(sf[qi][kj][r]);
        }
    }
    __syncthreads();                       /* P visible; Vt still valid */

    /* PV */
#pragma unroll
    for (int kk = 0; kk < 2; ++kk) {
      const int kgs = (kk << 2) + (lane >> 4);
      bf16x8 pf[2], vf[4];
#pragma unroll
      for (int qi = 0; qi < 2; ++qi) {
        const int pr = qi * 16 + (lane & 15);
        pf[qi] = *(const bf16x8*)(&Ps[w][pr * 64 + ((kgs ^ (pr & 7)) << 3)]);
      }
#pragma unroll
      for (int dj = 0; dj < 4; ++dj) {
        const int d = dj * 16 + (lane & 15);
        vf[dj] = *(const bf16x8*)(&Vt[d * 64 + ((kgs ^ (d & 7) ^ ((d >> 3) & 7)) << 3)]);
      }
#pragma unroll
      for (int qi = 0; qi < 2; ++qi)
#pragma unroll
        for (int dj = 0; dj < 4; ++dj)
          acc[qi][dj] = __builtin_amdgcn_mfma_f32_16x16x32_bf16(pf[qi], vf[dj], acc[qi][dj], 0, 0, 0);
    }
  }

  /* normalize + store ctx bf16 */
#pragma unroll
  for (int qi = 0; qi < 2; ++qi)
#pragma unroll
    for (int r = 0; r < 4; ++r) {
      const float inv = 1.f / l_run[qi][r];
      const int s = q0 + w * 32 + qi * 16 + ((lane >> 4) << 2) + r;
#pragma unroll
      for (int dj = 0; dj < 4; ++dj)
        O[base + (size_t)s * HDIM + dj * 16 + (lane & 15)] = f2bf(acc[qi][dj][r] * inv);
    }
}

/* ---- row LayerNorm over 1024, fp32 ---- */
__global__ void ln_kernel(const float* __restrict__ x, const float* __restrict__ g,
                          const float* __restrict__ bb, float* __restrict__ out) {
  const int row = blockIdx.x;
  const int tid = threadIdx.x;
  const f32x4 v = *(const f32x4*)(x + (size_t)row * HDIM + tid * 4);
  float s = v[0] + v[1] + v[2] + v[3];
  float s2 = v[0] * v[0] + v[1] * v[1] + v[2] * v[2] + v[3] * v[3];
#pragma unroll
  for (int o = 1; o < 64; o <<= 1) { s += __shfl_xor(s, o); s2 += __shfl_xor(s2, o); }
  __shared__ float rs[4], rs2[4];
  if ((tid & 63) == 0) { rs[tid >> 6] = s; rs2[tid >> 6] = s2; }
  __syncthreads();
  s = rs[0] + rs[1] + rs[2] + rs[3];
  s2 = rs2[0] + rs2[1] + rs2[2] + rs2[3];
  const float mu = s * (1.f / HDIM);
  const float var = s2 * (1.f / HDIM) - mu * mu;
  const float inv = rsqrtf(var + 1e-5f);
  f32x4 o4;
#pragma unroll
  for (int e = 0; e < 4; ++e) {
    const int c = tid * 4 + e;
    o4[e] = (v[e] - mu) * inv * g[c] + bb[c];
  }
  *(f32x4*)(out + (size_t)row * HDIM + tid * 4) = o4;
}

extern "C" void kernel_launch(void* const* d_in, const int* in_sizes, int n_in,
                              void* d_out, int out_size, void* d_ws, size_t ws_size,
                              hipStream_t stream) {
  const float* hidden = (const float*)d_in[0];
  const float* topic  = (const float*)d_in[1];
  const float* mask   = (const float*)d_in[2];
  const float* Wq  = (const float*)d_in[3];  const float* bq  = (const float*)d_in[4];
  const float* Wk  = (const float*)d_in[5];  const float* bk  = (const float*)d_in[6];
  const float* Wv  = (const float*)d_in[7];  const float* bv  = (const float*)d_in[8];
  const float* Wtp = (const float*)d_in[9];  const float* btp = (const float*)d_in[10];
  const float* Wta = (const float*)d_in[11]; const float* bta = (const float*)d_in[12];
  const float* Wd  = (const float*)d_in[13]; const float* bd  = (const float*)d_in[14];
  const float* lng = (const float*)d_in[15]; const float* lnb = (const float*)d_in[16];
  float* out = (float*)d_out;

  char* ws = (char*)d_ws;
  u16* hs_bf  = (u16*)(ws);                                  /* 8 MB  */
  u16* WtAll  = (u16*)(ws + (size_t)(8u << 20));             /* 8 MB: q,k,v,d */
  u16* qkv    = (u16*)(ws + (size_t)(16u << 20));            /* 24 MB */
  u16* ctx    = (u16*)(ws + (size_t)(40u << 20));            /* 8 MB  */
  float* xbuf = (float*)(ws + (size_t)(16u << 20));          /* aliases q,k after attn */
  float* tproj = (float*)(ws + (size_t)(48u << 20));
  float* tgate = (float*)(ws + (size_t)(48u << 20) + 8192);

  wt_bf16_kernel<<<dim3(32, 32, 4), dim3(32, 8), 0, stream>>>(Wq, Wk, Wv, Wd, WtAll);
  cvt_bf16_kernel<<<4096, 256, 0, stream>>>(hidden, hs_bf);
  topic_mm_kernel<<<dim3(16, NB), 256, 0, stream>>>(topic, Wtp, btp, tproj, 0);
  topic_mm_kernel<<<dim3(16, NB), 256, 0, stream>>>(tproj, Wta, bta, tgate, 1);
  gemm_kernel<0><<<dim3(8, 32, 3), 256, 0, stream>>>(hs_bf, WtAll, bq, bk, bv, tgate,
                                                     nullptr, qkv, nullptr);
  attn_kernel<<<dim3(16, 16, NB), 256, 0, stream>>>(qkv, qkv + (size_t)MROWS * HDIM,
                                                    qkv + 2 * (size_t)MROWS * HDIM, mask, ctx);
  gemm_kernel<1><<<dim3(8, 32, 1), 256, 0, stream>>>(ctx, WtAll + 3 * (size_t)HDIM * HDIM,
                                                     bd, nullptr, nullptr, nullptr, hidden,
                                                     nullptr, xbuf);
  ln_kernel<<<4096, 256, 0, stream>>>(xbuf, lng, lnb, out);
}

// Round 2
// 274.806 us; speedup vs baseline: 1.1780x; 1.1780x over previous
//
#include <hip/hip_runtime.h>

typedef unsigned short u16;
typedef unsigned int   u32;
typedef __attribute__((ext_vector_type(4)))  float f32x4;
typedef __attribute__((ext_vector_type(16))) float f32x16;
typedef __attribute__((ext_vector_type(8)))  __bf16 bf16x8;
typedef __attribute__((ext_vector_type(8)))  u16  u16x8;
typedef __attribute__((ext_vector_type(4)))  u16  u16x4;

#define HDIM 1024
#define SEQ  2048
#define NB   2
#define MROWS 4096   /* B*S */
#define QSCALE 0.18033688011111793f   /* 0.125 * log2(e) */
#define LOG2E  1.4426950408889634f

__device__ __forceinline__ u16 f2bf(float f) {
  u32 u = __float_as_uint(f);
  u32 r = u + 0x7FFFu + ((u >> 16) & 1u);
  return (u16)(r >> 16);
}

__device__ __forceinline__ u32 pkbf(float a, float b) {
  union { __bf16 h[2]; u32 w; } u;
  u.h[0] = (__bf16)a; u.h[1] = (__bf16)b;
  return u.w;
}

__device__ __forceinline__ void gload_lds16(const void* gp, void* lp) {
  __builtin_amdgcn_global_load_lds(
      (const __attribute__((address_space(1))) void*)gp,
      (__attribute__((address_space(3))) void*)lp, 16, 0, 0);
}

/* ---- weights fp32 [K][N] -> bf16 transposed [N][K], 4 matrices ---- */
__global__ void wt_bf16_kernel(const float* __restrict__ w0, const float* __restrict__ w1,
                               const float* __restrict__ w2, const float* __restrict__ w3,
                               u16* __restrict__ out) {
  const float* W = (blockIdx.z == 0) ? w0 : (blockIdx.z == 1) ? w1 : (blockIdx.z == 2) ? w2 : w3;
  u16* Wt = out + (size_t)blockIdx.z * HDIM * HDIM;
  __shared__ float t[32][33];
  const int k0 = blockIdx.x * 32, n0 = blockIdx.y * 32;
  const int tx = threadIdx.x, ty = threadIdx.y;
#pragma unroll
  for (int j = 0; j < 32; j += 8)
    t[ty + j][tx] = W[(size_t)(k0 + ty + j) * HDIM + n0 + tx];
  __syncthreads();
#pragma unroll
  for (int j = 0; j < 32; j += 8)
    Wt[(size_t)(n0 + ty + j) * HDIM + k0 + tx] = f2bf(t[tx][ty + j]);
}

/* ---- fp32 -> bf16, 4 elems/thread ---- */
__global__ void cvt_bf16_kernel(const float* __restrict__ in, u16* __restrict__ out) {
  const size_t i = (size_t)blockIdx.x * 256 + threadIdx.x;
  f32x4 v = *(const f32x4*)(in + i * 4);
  u16x4 o;
#pragma unroll
  for (int e = 0; e < 4; ++e) o[e] = f2bf(v[e]);
  *(u16x4*)(out + i * 4) = o;
}

/* ---- mask * log2e ---- */
__global__ void maskcvt_kernel(const float* __restrict__ m, float* __restrict__ o) {
  const int i = blockIdx.x * 256 + threadIdx.x;
  o[i] = m[i] * LOG2E;
}

/* ---- tiny topic GEMV: out[b][n] = act(in[b]·W[:,n] + bias[n]) ---- */
__global__ void topic_mm_kernel(const float* __restrict__ in, const float* __restrict__ W,
                                const float* __restrict__ bias, float* __restrict__ out,
                                int sigmoid_mode) {
  const int b = blockIdx.y;
  const int n = blockIdx.x * 64 + (threadIdx.x & 63);
  const int kc = threadIdx.x >> 6;
  const float* inb = in + b * HDIM;
  float s = 0.f;
  for (int k = kc * 256; k < kc * 256 + 256; ++k)
    s += inb[k] * W[(size_t)k * HDIM + n];
  __shared__ float red[256];
  red[threadIdx.x] = s;
  __syncthreads();
  if (threadIdx.x < 64) {
    float t = red[threadIdx.x] + red[threadIdx.x + 64] + red[threadIdx.x + 128] +
              red[threadIdx.x + 192] + bias[n];
    out[b * HDIM + n] = sigmoid_mode ? (1.f / (1.f + __expf(-t))) : t;
  }
}

/* ---- 128x128 bf16 MFMA GEMM.  A [M][1024] bf16, Wt [N][K] bf16.
   MODE 0: z in {0,1,2} = q,k,v; bias per z; z==0 scales by QSCALE, z==1 gate; bf16 out.
   MODE 1: bias + residual, fp32 out. ---- */
template <int MODE>
__global__ __launch_bounds__(256, 2)
void gemm_kernel(const u16* __restrict__ A, const u16* __restrict__ Wt,
                 const float* __restrict__ b0, const float* __restrict__ b1,
                 const float* __restrict__ b2, const float* __restrict__ gate,
                 const float* __restrict__ resid,
                 u16* __restrict__ outb, float* __restrict__ outf) {
  const int n0 = blockIdx.x * 128;
  const int m0 = blockIdx.y * 128;
  const int z = blockIdx.z;
  const u16* W = Wt + (size_t)z * (HDIM * HDIM);
  const float* bias = (MODE == 0) ? (z == 0 ? b0 : (z == 1 ? b1 : b2)) : b0;

  __shared__ __align__(16) u16 Alds[128 * 64];
  __shared__ __align__(16) u16 Blds[128 * 64];

  const int tid = threadIdx.x;
  const int lane = tid & 63;
  const int w = tid >> 6;
  const int wm = w >> 1, wn = w & 1;
  const int srow = tid >> 3, sslot = tid & 7;

  f32x4 acc[4][4] = {};

  for (int k0 = 0; k0 < HDIM; k0 += 64) {
    __syncthreads();
#pragma unroll
    for (int j = 0; j < 4; ++j) {
      const int row = j * 32 + srow;
      const int gs = (sslot ^ (row & 7)) * 8;   /* inverse-swizzled global source */
      gload_lds16(A + (size_t)(m0 + row) * HDIM + k0 + gs, Alds + j * 2048 + w * 512);
      gload_lds16(W + (size_t)(n0 + row) * HDIM + k0 + gs, Blds + j * 2048 + w * 512);
    }
    __syncthreads();
#pragma unroll
    for (int kk = 0; kk < 2; ++kk) {
      const int slot = ((((kk << 2) + (lane >> 4)) ^ (lane & 7)) << 3); /* swizzled read */
      bf16x8 af[4], bfr[4];
#pragma unroll
      for (int i = 0; i < 4; ++i) {
        af[i]  = *(const bf16x8*)(&Alds[(wm * 64 + i * 16 + (lane & 15)) * 64 + slot]);
        bfr[i] = *(const bf16x8*)(&Blds[(wn * 64 + i * 16 + (lane & 15)) * 64 + slot]);
      }
#pragma unroll
      for (int i = 0; i < 4; ++i)
#pragma unroll
        for (int jn = 0; jn < 4; ++jn)
          acc[i][jn] = __builtin_amdgcn_mfma_f32_16x16x32_bf16(af[i], bfr[jn], acc[i][jn], 0, 0, 0);
    }
  }

  const int rbase = (lane >> 4) << 2;
#pragma unroll
  for (int i = 0; i < 4; ++i) {
#pragma unroll
    for (int jn = 0; jn < 4; ++jn) {
      const int n = n0 + wn * 64 + jn * 16 + (lane & 15);
      const float bv = bias[n];
#pragma unroll
      for (int r = 0; r < 4; ++r) {
        const int m = m0 + wm * 64 + i * 16 + rbase + r;
        float v = acc[i][jn][r] + bv;
        if (MODE == 0) {
          if (z == 0) v *= QSCALE;
          if (z == 1) v *= gate[(m >> 11) * HDIM + n];
          outb[(size_t)z * MROWS * HDIM + (size_t)m * HDIM + n] = f2bf(v);
        } else {
          v += resid[(size_t)m * HDIM + n];
          outf[(size_t)m * HDIM + n] = v;
        }
      }
    }
  }
}

/* ---- flash attention v2: swapped QK^T (S^T = mfma(K,Q)) with 32x32x16 MFMA.
   4 waves x 32 q-rows = 128 q/block; KVBLK=64 double-buffered.
   Lane owns q = lane&31; in-register softmax (exp2 domain); P-frag built via
   pack + shfl_xor(32); defer-max rescale (THR=8). ---- */
__global__ __launch_bounds__(256, 2)
void attn_kernel(const u16* __restrict__ Q, const u16* __restrict__ K,
                 const u16* __restrict__ V, const float* __restrict__ mask2,
                 u16* __restrict__ O) {
  const int q0 = blockIdx.x * 128;
  const int h = blockIdx.y;
  const int b = blockIdx.z;
  const size_t base = ((size_t)b * SEQ) * HDIM + h * 64;
  const int tid = threadIdx.x, lane = tid & 63, w = tid >> 6;
  const int hh = lane >> 5;         /* half of wave */
  const int ql = lane & 31;         /* q-col (B), kv-row (A), d-col (PV B) */
  const int srow = tid >> 3, sslot = tid & 7;

  __shared__ __align__(16) u16 Kss[2][64 * 64];
  __shared__ __align__(16) u16 Vts[2][64 * 64];   /* [d][kv], XOR-swizzled */

  /* Q fragments in registers: B-frag lane holds Q[q=ql][d = ds*16 + hh*8 + e] */
  bf16x8 Qf[4];
  {
    const u16* qp = Q + base + (size_t)(q0 + w * 32 + ql) * HDIM;
#pragma unroll
    for (int ds = 0; ds < 4; ++ds)
      Qf[ds] = *(const bf16x8*)(qp + ds * 16 + hh * 8);
  }

  float m_run = -1e30f, l_run = 0.f;
  f32x16 accA = {}, accB = {};

  /* prologue staging of tile 0 */
  {
#pragma unroll
    for (int c = 0; c < 2; ++c) {
      const int i2 = c * 4 + w;
      const int row = i2 * 8 + (lane >> 3);
      const int sl = lane & 7;
      gload_lds16(K + base + (size_t)row * HDIM + ((sl ^ (row & 7)) * 8),
                  &Kss[0][i2 * 512]);
    }
    u16x8 vr[2];
#pragma unroll
    for (int jj = 0; jj < 2; ++jj)
      vr[jj] = *(const u16x8*)(V + base + (size_t)(jj * 32 + srow) * HDIM + sslot * 8);
#pragma unroll
    for (int jj = 0; jj < 2; ++jj) {
      const int kr = jj * 32 + srow;
#pragma unroll
      for (int e = 0; e < 8; ++e) {
        const int d = sslot * 8 + e;
        Vts[0][d * 64 + ((((kr >> 3) ^ (d & 7) ^ ((d >> 3) & 7))) << 3) + (kr & 7)] = vr[jj][e];
      }
    }
  }
  __syncthreads();

  for (int t = 0; t < SEQ / 64; ++t) {
    const int cur = t & 1;
    const int kvt0 = t * 64;
    u16x8 vr[2];
    if (t + 1 < SEQ / 64) {
      /* issue next-tile global loads early (hide under compute) */
#pragma unroll
      for (int jj = 0; jj < 2; ++jj)
        vr[jj] = *(const u16x8*)(V + base + (size_t)(kvt0 + 64 + jj * 32 + srow) * HDIM + sslot * 8);
#pragma unroll
      for (int c = 0; c < 2; ++c) {
        const int i2 = c * 4 + w;
        const int row = i2 * 8 + (lane >> 3);
        const int sl = lane & 7;
        gload_lds16(K + base + (size_t)(kvt0 + 64 + row) * HDIM + ((sl ^ (row & 7)) * 8),
                    &Kss[cur ^ 1][i2 * 512]);
      }
    }

#pragma unroll
    for (int kvb = 0; kvb < 2; ++kvb) {
      /* ---- QK^T: S^T = mfma(K, Q) over 4 d-steps ---- */
      f32x16 sv = {};
#pragma unroll
      for (int ds = 0; ds < 4; ++ds) {
        const bf16x8 kf = *(const bf16x8*)(
            &Kss[cur][(kvb * 32 + ql) * 64 + (((ds * 2 + hh) ^ (ql & 7)) << 3)]);
        sv = __builtin_amdgcn_mfma_f32_32x32x16_bf16(kf, Qf[ds], sv, 0, 0, 0);
      }
      /* mask (already * log2e); lane's kv rows = (j&3)+8*(j>>2)+4*hh */
      f32x4 m4[4];
      {
        const float* mrow = mask2 + (size_t)b * SEQ + kvt0 + kvb * 32 + hh * 4;
#pragma unroll
        for (int g = 0; g < 4; ++g) m4[g] = *(const f32x4*)(mrow + g * 8);
      }
      f32x16 s_;
#pragma unroll
      for (int j = 0; j < 16; ++j) s_[j] = sv[j] + m4[j >> 2][j & 3];

      /* row max over 32 kv (16 local + cross-half) */
      float mx0 = fmaxf(fmaxf(s_[0], s_[1]), fmaxf(s_[2], s_[3]));
      float mx1 = fmaxf(fmaxf(s_[4], s_[5]), fmaxf(s_[6], s_[7]));
      float mx2 = fmaxf(fmaxf(s_[8], s_[9]), fmaxf(s_[10], s_[11]));
      float mx3 = fmaxf(fmaxf(s_[12], s_[13]), fmaxf(s_[14], s_[15]));
      float mx = fmaxf(fmaxf(mx0, mx1), fmaxf(mx2, mx3));
      mx = fmaxf(mx, __shfl_xor(mx, 32));

      if (!__all(mx <= m_run + 8.f)) {     /* defer-max: rescale rarely */
        const float mnew = fmaxf(m_run, mx);
        const float corr = __builtin_amdgcn_exp2f(m_run - mnew);
        m_run = mnew;
        l_run *= corr;
#pragma unroll
        for (int j = 0; j < 16; ++j) {
          const float cj = __shfl(corr, (j & 3) + 8 * (j >> 2) + 4 * hh);
          accA[j] *= cj; accB[j] *= cj;
        }
      }

      f32x16 p_;
#pragma unroll
      for (int j = 0; j < 16; ++j) p_[j] = __builtin_amdgcn_exp2f(s_[j] - m_run);
      {
        float r0 = (p_[0] + p_[1]) + (p_[2] + p_[3]);
        float r1 = (p_[4] + p_[5]) + (p_[6] + p_[7]);
        float r2 = (p_[8] + p_[9]) + (p_[10] + p_[11]);
        float r3 = (p_[12] + p_[13]) + (p_[14] + p_[15]);
        float rs = (r0 + r1) + (r2 + r3);
        rs += __shfl_xor(rs, 32);
        l_run += rs;
      }

      /* ---- PV: assemble P A-frags in-register, 2 k-steps of 16 ---- */
#pragma unroll
      for (int s2 = 0; s2 < 2; ++s2) {
        const u32 a0 = pkbf(p_[s2 * 8 + 0], p_[s2 * 8 + 1]);
        const u32 a1 = pkbf(p_[s2 * 8 + 2], p_[s2 * 8 + 3]);
        const u32 b0v = pkbf(p_[s2 * 8 + 4], p_[s2 * 8 + 5]);
        const u32 b1v = pkbf(p_[s2 * 8 + 6], p_[s2 * 8 + 7]);
        const u32 sd0 = hh ? a0 : b0v, sd1 = hh ? a1 : b1v;
        const u32 r0 = (u32)__shfl_xor((int)sd0, 32);
        const u32 r1 = (u32)__shfl_xor((int)sd1, 32);
        union { u32 u[4]; bf16x8 v; } pu;
        pu.u[0] = hh ? r0 : a0;  pu.u[1] = hh ? r1 : a1;
        pu.u[2] = hh ? b0v : r0; pu.u[3] = hh ? b1v : r1;
        const int ks = kvb * 4 + s2 * 2 + hh;
#pragma unroll
        for (int dt = 0; dt < 2; ++dt) {
          const int d = dt * 32 + ql;
          const bf16x8 vf = *(const bf16x8*)(
              &Vts[cur][d * 64 + ((ks ^ (d & 7) ^ ((d >> 3) & 7)) << 3)]);
          if (dt == 0) accA = __builtin_amdgcn_mfma_f32_32x32x16_bf16(pu.v, vf, accA, 0, 0, 0);
          else         accB = __builtin_amdgcn_mfma_f32_32x32x16_bf16(pu.v, vf, accB, 0, 0, 0);
        }
      }
    }

    if (t + 1 < SEQ / 64) {   /* V writes after compute (loads have landed) */
#pragma unroll
      for (int jj = 0; jj < 2; ++jj) {
        const int kr = jj * 32 + srow;
#pragma unroll
        for (int e = 0; e < 8; ++e) {
          const int d = sslot * 8 + e;
          Vts[cur ^ 1][d * 64 + ((((kr >> 3) ^ (d & 7) ^ ((d >> 3) & 7))) << 3) + (kr & 7)] = vr[jj][e];
        }
      }
    }
    __syncthreads();
  }

  /* epilogue: ctx = acc / l, scatter per C/D row map */
  const float linv = 1.f / l_run;
#pragma unroll
  for (int j = 0; j < 16; ++j) {
    const int rq = (j & 3) + 8 * (j >> 2) + 4 * hh;
    const float lj = __shfl(linv, rq);
    const size_t orow = base + (size_t)(q0 + w * 32 + rq) * HDIM;
    O[orow + ql]      = f2bf(accA[j] * lj);
    O[orow + 32 + ql] = f2bf(accB[j] * lj);
  }
}

/* ---- row LayerNorm over 1024, fp32 ---- */
__global__ void ln_kernel(const float* __restrict__ x, const float* __restrict__ g,
                          const float* __restrict__ bb, float* __restrict__ out) {
  const int row = blockIdx.x;
  const int tid = threadIdx.x;
  const f32x4 v = *(const f32x4*)(x + (size_t)row * HDIM + tid * 4);
  float s = v[0] + v[1] + v[2] + v[3];
  float s2 = v[0] * v[0] + v[1] * v[1] + v[2] * v[2] + v[3] * v[3];
#pragma unroll
  for (int o = 1; o < 64; o <<= 1) { s += __shfl_xor(s, o); s2 += __shfl_xor(s2, o); }
  __shared__ float rs[4], rs2[4];
  if ((tid & 63) == 0) { rs[tid >> 6] = s; rs2[tid >> 6] = s2; }
  __syncthreads();
  s = rs[0] + rs[1] + rs[2] + rs[3];
  s2 = rs2[0] + rs2[1] + rs2[2] + rs2[3];
  const float mu = s * (1.f / HDIM);
  const float var = s2 * (1.f / HDIM) - mu * mu;
  const float inv = rsqrtf(var + 1e-5f);
  f32x4 o4;
#pragma unroll
  for (int e = 0; e < 4; ++e) {
    const int c = tid * 4 + e;
    o4[e] = (v[e] - mu) * inv * g[c] + bb[c];
  }
  *(f32x4*)(out + (size_t)row * HDIM + tid * 4) = o4;
}

extern "C" void kernel_launch(void* const* d_in, const int* in_sizes, int n_in,
                              void* d_out, int out_size, void* d_ws, size_t ws_size,
                              hipStream_t stream) {
  const float* hidden = (const float*)d_in[0];
  const float* topic  = (const float*)d_in[1];
  const float* mask   = (const float*)d_in[2];
  const float* Wq  = (const float*)d_in[3];  const float* bq  = (const float*)d_in[4];
  const float* Wk  = (const float*)d_in[5];  const float* bk  = (const float*)d_in[6];
  const float* Wv  = (const float*)d_in[7];  const float* bv  = (const float*)d_in[8];
  const float* Wtp = (const float*)d_in[9];  const float* btp = (const float*)d_in[10];
  const float* Wta = (const float*)d_in[11]; const float* bta = (const float*)d_in[12];
  const float* Wd  = (const float*)d_in[13]; const float* bd  = (const float*)d_in[14];
  const float* lng = (const float*)d_in[15]; const float* lnb = (const float*)d_in[16];
  float* out = (float*)d_out;

  char* ws = (char*)d_ws;
  u16* hs_bf  = (u16*)(ws);                                  /* 8 MB  */
  u16* WtAll  = (u16*)(ws + (size_t)(8u << 20));             /* 8 MB: q,k,v,d */
  u16* qkv    = (u16*)(ws + (size_t)(16u << 20));            /* 24 MB */
  u16* ctx    = (u16*)(ws + (size_t)(40u << 20));            /* 8 MB  */
  float* xbuf = (float*)(ws + (size_t)(16u << 20));          /* aliases q,k after attn */
  float* tproj = (float*)(ws + (size_t)(48u << 20));
  float* tgate = (float*)(ws + (size_t)(48u << 20) + 8192);
  float* mask2 = (float*)(ws + (size_t)(48u << 20));         /* aliases tproj+tgate (dead by then) */

  wt_bf16_kernel<<<dim3(32, 32, 4), dim3(32, 8), 0, stream>>>(Wq, Wk, Wv, Wd, WtAll);
  cvt_bf16_kernel<<<4096, 256, 0, stream>>>(hidden, hs_bf);
  topic_mm_kernel<<<dim3(16, NB), 256, 0, stream>>>(topic, Wtp, btp, tproj, 0);
  topic_mm_kernel<<<dim3(16, NB), 256, 0, stream>>>(tproj, Wta, bta, tgate, 1);
  gemm_kernel<0><<<dim3(8, 32, 3), 256, 0, stream>>>(hs_bf, WtAll, bq, bk, bv, tgate,
                                                     nullptr, qkv, nullptr);
  maskcvt_kernel<<<16, 256, 0, stream>>>(mask, mask2);
  attn_kernel<<<dim3(16, 16, NB), 256, 0, stream>>>(qkv, qkv + (size_t)MROWS * HDIM,
                                                    qkv + 2 * (size_t)MROWS * HDIM, mask2, ctx);
  gemm_kernel<1><<<dim3(8, 32, 1), 256, 0, stream>>>(ctx, WtAll + 3 * (size_t)HDIM * HDIM,
                                                     bd, nullptr, nullptr, nullptr, hidden,
                                                     nullptr, xbuf);
  ln_kernel<<<4096, 256, 0, stream>>>(xbuf, lng, lnb, out);
}

// Round 3
// 163.931 us; speedup vs baseline: 1.9747x; 1.6764x over previous
//
#include <hip/hip_runtime.h>

typedef unsigned short u16;
typedef unsigned int   u32;
typedef __attribute__((ext_vector_type(4)))  float f32x4;
typedef __attribute__((ext_vector_type(16))) float f32x16;
typedef __attribute__((ext_vector_type(8)))  __bf16 bf16x8;
typedef __attribute__((ext_vector_type(8)))  u16  u16x8;
typedef __attribute__((ext_vector_type(4)))  u16  u16x4;

#define HDIM 1024
#define SEQ  2048
#define NB   2
#define MROWS 4096   /* B*S */
#define QSCALE 0.18033688011111793f   /* 0.125 * log2(e) */
#define LOG2E  1.4426950408889634f
#define TOPK 64      /* k-rows per split-k chunk */
#define TOPC 16      /* chunks */

__device__ __forceinline__ u16 f2bf(float f) {
  u32 u = __float_as_uint(f);
  u32 r = u + 0x7FFFu + ((u >> 16) & 1u);
  return (u16)(r >> 16);
}

__device__ __forceinline__ u32 pkbf(float a, float b) {
  union { __bf16 h[2]; u32 w; } u;
  u.h[0] = (__bf16)a; u.h[1] = (__bf16)b;
  return u.w;
}

__device__ __forceinline__ void gload_lds16(const void* gp, void* lp) {
  __builtin_amdgcn_global_load_lds(
      (const __attribute__((address_space(1))) void*)gp,
      (__attribute__((address_space(3))) void*)lp, 16, 0, 0);
}

/* ---- weights fp32 [K][N] -> bf16 transposed [N][K], 4 matrices ---- */
__global__ void wt_bf16_kernel(const float* __restrict__ w0, const float* __restrict__ w1,
                               const float* __restrict__ w2, const float* __restrict__ w3,
                               u16* __restrict__ out) {
  const float* W = (blockIdx.z == 0) ? w0 : (blockIdx.z == 1) ? w1 : (blockIdx.z == 2) ? w2 : w3;
  u16* Wt = out + (size_t)blockIdx.z * HDIM * HDIM;
  __shared__ float t[32][33];
  const int k0 = blockIdx.x * 32, n0 = blockIdx.y * 32;
  const int tx = threadIdx.x, ty = threadIdx.y;
#pragma unroll
  for (int j = 0; j < 32; j += 8)
    t[ty + j][tx] = W[(size_t)(k0 + ty + j) * HDIM + n0 + tx];
  __syncthreads();
#pragma unroll
  for (int j = 0; j < 32; j += 8)
    Wt[(size_t)(n0 + ty + j) * HDIM + k0 + tx] = f2bf(t[tx][ty + j]);
}

/* ---- fp32 -> bf16, 4 elems/thread ---- */
__global__ void cvt_bf16_kernel(const float* __restrict__ in, u16* __restrict__ out) {
  const size_t i = (size_t)blockIdx.x * 256 + threadIdx.x;
  f32x4 v = *(const f32x4*)(in + i * 4);
  u16x4 o;
#pragma unroll
  for (int e = 0; e < 4; ++e) o[e] = f2bf(v[e]);
  *(u16x4*)(out + i * 4) = o;
}

/* ---- mask * log2e ---- */
__global__ void maskcvt_kernel(const float* __restrict__ m, float* __restrict__ o) {
  const int i = blockIdx.x * 256 + threadIdx.x;
  o[i] = m[i] * LOG2E;
}

/* ---- topic GEMV stage A: part[b][c][n] = sum_{k in chunk c} in[b][k]*W[k][n].
   Thread owns n-quad; 64 coalesced independent f32x4 loads -> high MLP. ---- */
__global__ void topic_partial_kernel(const float* __restrict__ in, const float* __restrict__ W,
                                     float* __restrict__ part) {
  const int c = blockIdx.x;
  const int b = blockIdx.y;
  const int t = threadIdx.x;
  const float* inb = in + b * HDIM + c * TOPK;
  f32x4 acc = {};
#pragma unroll 8
  for (int k = 0; k < TOPK; ++k) {
    const f32x4 w4 = *(const f32x4*)(W + (size_t)(c * TOPK + k) * HDIM + t * 4);
    acc += inb[k] * w4;
  }
  *(f32x4*)(part + ((size_t)(b * TOPC + c)) * HDIM + t * 4) = acc;
}

/* ---- topic GEMV stage B: reduce chunks + bias (+ sigmoid) ---- */
__global__ void topic_reduce_kernel(const float* __restrict__ part, const float* __restrict__ bias,
                                    float* __restrict__ out, int sigmoid_mode) {
  const int b = blockIdx.y;
  const int n = blockIdx.x * 256 + threadIdx.x;
  float s = bias[n];
#pragma unroll
  for (int c = 0; c < TOPC; ++c) s += part[((size_t)(b * TOPC + c)) * HDIM + n];
  out[b * HDIM + n] = sigmoid_mode ? (1.f / (1.f + __expf(-s))) : s;
}

/* ---- 128x128 bf16 MFMA GEMM.  A [M][1024] bf16, Wt [N][K] bf16.
   MODE 0: z in {0,1,2} = q,k,v; bias per z; z==0 scales by QSCALE, z==1 gate; bf16 out.
   MODE 1: bias + residual, fp32 out. ---- */
template <int MODE>
__global__ __launch_bounds__(256, 2)
void gemm_kernel(const u16* __restrict__ A, const u16* __restrict__ Wt,
                 const float* __restrict__ b0, const float* __restrict__ b1,
                 const float* __restrict__ b2, const float* __restrict__ gate,
                 const float* __restrict__ resid,
                 u16* __restrict__ outb, float* __restrict__ outf) {
  const int n0 = blockIdx.x * 128;
  const int m0 = blockIdx.y * 128;
  const int z = blockIdx.z;
  const u16* W = Wt + (size_t)z * (HDIM * HDIM);
  const float* bias = (MODE == 0) ? (z == 0 ? b0 : (z == 1 ? b1 : b2)) : b0;

  __shared__ __align__(16) u16 Alds[128 * 64];
  __shared__ __align__(16) u16 Blds[128 * 64];

  const int tid = threadIdx.x;
  const int lane = tid & 63;
  const int w = tid >> 6;
  const int wm = w >> 1, wn = w & 1;
  const int srow = tid >> 3, sslot = tid & 7;

  f32x4 acc[4][4] = {};

  for (int k0 = 0; k0 < HDIM; k0 += 64) {
    __syncthreads();
#pragma unroll
    for (int j = 0; j < 4; ++j) {
      const int row = j * 32 + srow;
      const int gs = (sslot ^ (row & 7)) * 8;   /* inverse-swizzled global source */
      gload_lds16(A + (size_t)(m0 + row) * HDIM + k0 + gs, Alds + j * 2048 + w * 512);
      gload_lds16(W + (size_t)(n0 + row) * HDIM + k0 + gs, Blds + j * 2048 + w * 512);
    }
    __syncthreads();
#pragma unroll
    for (int kk = 0; kk < 2; ++kk) {
      const int slot = ((((kk << 2) + (lane >> 4)) ^ (lane & 7)) << 3); /* swizzled read */
      bf16x8 af[4], bfr[4];
#pragma unroll
      for (int i = 0; i < 4; ++i) {
        af[i]  = *(const bf16x8*)(&Alds[(wm * 64 + i * 16 + (lane & 15)) * 64 + slot]);
        bfr[i] = *(const bf16x8*)(&Blds[(wn * 64 + i * 16 + (lane & 15)) * 64 + slot]);
      }
#pragma unroll
      for (int i = 0; i < 4; ++i)
#pragma unroll
        for (int jn = 0; jn < 4; ++jn)
          acc[i][jn] = __builtin_amdgcn_mfma_f32_16x16x32_bf16(af[i], bfr[jn], acc[i][jn], 0, 0, 0);
    }
  }

  const int rbase = (lane >> 4) << 2;
#pragma unroll
  for (int i = 0; i < 4; ++i) {
#pragma unroll
    for (int jn = 0; jn < 4; ++jn) {
      const int n = n0 + wn * 64 + jn * 16 + (lane & 15);
      const float bv = bias[n];
#pragma unroll
      for (int r = 0; r < 4; ++r) {
        const int m = m0 + wm * 64 + i * 16 + rbase + r;
        float v = acc[i][jn][r] + bv;
        if (MODE == 0) {
          if (z == 0) v *= QSCALE;
          if (z == 1) v *= gate[(m >> 11) * HDIM + n];
          outb[(size_t)z * MROWS * HDIM + (size_t)m * HDIM + n] = f2bf(v);
        } else {
          v += resid[(size_t)m * HDIM + n];
          outf[(size_t)m * HDIM + n] = v;
        }
      }
    }
  }
}

/* ---- flash attention v2: swapped QK^T (S^T = mfma(K,Q)) with 32x32x16 MFMA.
   4 waves x 32 q-rows = 128 q/block; KVBLK=64 double-buffered.
   Lane owns q = lane&31; in-register softmax (exp2 domain); P-frag built via
   pack + shfl_xor(32); defer-max rescale (THR=8). ---- */
__global__ __launch_bounds__(256, 2)
void attn_kernel(const u16* __restrict__ Q, const u16* __restrict__ K,
                 const u16* __restrict__ V, const float* __restrict__ mask2,
                 u16* __restrict__ O) {
  const int q0 = blockIdx.x * 128;
  const int h = blockIdx.y;
  const int b = blockIdx.z;
  const size_t base = ((size_t)b * SEQ) * HDIM + h * 64;
  const int tid = threadIdx.x, lane = tid & 63, w = tid >> 6;
  const int hh = lane >> 5;         /* half of wave */
  const int ql = lane & 31;         /* q-col (B), kv-row (A), d-col (PV B) */
  const int srow = tid >> 3, sslot = tid & 7;

  __shared__ __align__(16) u16 Kss[2][64 * 64];
  __shared__ __align__(16) u16 Vts[2][64 * 64];   /* [d][kv], XOR-swizzled */

  /* Q fragments in registers: B-frag lane holds Q[q=ql][d = ds*16 + hh*8 + e] */
  bf16x8 Qf[4];
  {
    const u16* qp = Q + base + (size_t)(q0 + w * 32 + ql) * HDIM;
#pragma unroll
    for (int ds = 0; ds < 4; ++ds)
      Qf[ds] = *(const bf16x8*)(qp + ds * 16 + hh * 8);
  }

  float m_run = -1e30f, l_run = 0.f;
  f32x16 accA = {}, accB = {};

  /* prologue staging of tile 0 */
  {
#pragma unroll
    for (int c = 0; c < 2; ++c) {
      const int i2 = c * 4 + w;
      const int row = i2 * 8 + (lane >> 3);
      const int sl = lane & 7;
      gload_lds16(K + base + (size_t)row * HDIM + ((sl ^ (row & 7)) * 8),
                  &Kss[0][i2 * 512]);
    }
    u16x8 vr[2];
#pragma unroll
    for (int jj = 0; jj < 2; ++jj)
      vr[jj] = *(const u16x8*)(V + base + (size_t)(jj * 32 + srow) * HDIM + sslot * 8);
#pragma unroll
    for (int jj = 0; jj < 2; ++jj) {
      const int kr = jj * 32 + srow;
#pragma unroll
      for (int e = 0; e < 8; ++e) {
        const int d = sslot * 8 + e;
        Vts[0][d * 64 + ((((kr >> 3) ^ (d & 7) ^ ((d >> 3) & 7))) << 3) + (kr & 7)] = vr[jj][e];
      }
    }
  }
  __syncthreads();

  for (int t = 0; t < SEQ / 64; ++t) {
    const int cur = t & 1;
    const int kvt0 = t * 64;
    u16x8 vr[2];
    if (t + 1 < SEQ / 64) {
      /* issue next-tile global loads early (hide under compute) */
#pragma unroll
      for (int jj = 0; jj < 2; ++jj)
        vr[jj] = *(const u16x8*)(V + base + (size_t)(kvt0 + 64 + jj * 32 + srow) * HDIM + sslot * 8);
#pragma unroll
      for (int c = 0; c < 2; ++c) {
        const int i2 = c * 4 + w;
        const int row = i2 * 8 + (lane >> 3);
        const int sl = lane & 7;
        gload_lds16(K + base + (size_t)(kvt0 + 64 + row) * HDIM + ((sl ^ (row & 7)) * 8),
                    &Kss[cur ^ 1][i2 * 512]);
      }
    }

#pragma unroll
    for (int kvb = 0; kvb < 2; ++kvb) {
      /* ---- QK^T: S^T = mfma(K, Q) over 4 d-steps ---- */
      f32x16 sv = {};
#pragma unroll
      for (int ds = 0; ds < 4; ++ds) {
        const bf16x8 kf = *(const bf16x8*)(
            &Kss[cur][(kvb * 32 + ql) * 64 + (((ds * 2 + hh) ^ (ql & 7)) << 3)]);
        sv = __builtin_amdgcn_mfma_f32_32x32x16_bf16(kf, Qf[ds], sv, 0, 0, 0);
      }
      /* mask (already * log2e); lane's kv rows = (j&3)+8*(j>>2)+4*hh */
      f32x4 m4[4];
      {
        const float* mrow = mask2 + (size_t)b * SEQ + kvt0 + kvb * 32 + hh * 4;
#pragma unroll
        for (int g = 0; g < 4; ++g) m4[g] = *(const f32x4*)(mrow + g * 8);
      }
      f32x16 s_;
#pragma unroll
      for (int j = 0; j < 16; ++j) s_[j] = sv[j] + m4[j >> 2][j & 3];

      /* row max over 32 kv (16 local + cross-half) */
      float mx0 = fmaxf(fmaxf(s_[0], s_[1]), fmaxf(s_[2], s_[3]));
      float mx1 = fmaxf(fmaxf(s_[4], s_[5]), fmaxf(s_[6], s_[7]));
      float mx2 = fmaxf(fmaxf(s_[8], s_[9]), fmaxf(s_[10], s_[11]));
      float mx3 = fmaxf(fmaxf(s_[12], s_[13]), fmaxf(s_[14], s_[15]));
      float mx = fmaxf(fmaxf(mx0, mx1), fmaxf(mx2, mx3));
      mx = fmaxf(mx, __shfl_xor(mx, 32));

      if (!__all(mx <= m_run + 8.f)) {     /* defer-max: rescale rarely */
        const float mnew = fmaxf(m_run, mx);
        const float corr = __builtin_amdgcn_exp2f(m_run - mnew);
        m_run = mnew;
        l_run *= corr;
#pragma unroll
        for (int j = 0; j < 16; ++j) {
          const float cj = __shfl(corr, (j & 3) + 8 * (j >> 2) + 4 * hh);
          accA[j] *= cj; accB[j] *= cj;
        }
      }

      f32x16 p_;
#pragma unroll
      for (int j = 0; j < 16; ++j) p_[j] = __builtin_amdgcn_exp2f(s_[j] - m_run);
      {
        float r0 = (p_[0] + p_[1]) + (p_[2] + p_[3]);
        float r1 = (p_[4] + p_[5]) + (p_[6] + p_[7]);
        float r2 = (p_[8] + p_[9]) + (p_[10] + p_[11]);
        float r3 = (p_[12] + p_[13]) + (p_[14] + p_[15]);
        float rs = (r0 + r1) + (r2 + r3);
        rs += __shfl_xor(rs, 32);
        l_run += rs;
      }

      /* ---- PV: assemble P A-frags in-register, 2 k-steps of 16 ---- */
#pragma unroll
      for (int s2 = 0; s2 < 2; ++s2) {
        const u32 a0 = pkbf(p_[s2 * 8 + 0], p_[s2 * 8 + 1]);
        const u32 a1 = pkbf(p_[s2 * 8 + 2], p_[s2 * 8 + 3]);
        const u32 b0v = pkbf(p_[s2 * 8 + 4], p_[s2 * 8 + 5]);
        const u32 b1v = pkbf(p_[s2 * 8 + 6], p_[s2 * 8 + 7]);
        const u32 sd0 = hh ? a0 : b0v, sd1 = hh ? a1 : b1v;
        const u32 r0 = (u32)__shfl_xor((int)sd0, 32);
        const u32 r1 = (u32)__shfl_xor((int)sd1, 32);
        union { u32 u[4]; bf16x8 v; } pu;
        pu.u[0] = hh ? r0 : a0;  pu.u[1] = hh ? r1 : a1;
        pu.u[2] = hh ? b0v : r0; pu.u[3] = hh ? b1v : r1;
        const int ks = kvb * 4 + s2 * 2 + hh;
#pragma unroll
        for (int dt = 0; dt < 2; ++dt) {
          const int d = dt * 32 + ql;
          const bf16x8 vf = *(const bf16x8*)(
              &Vts[cur][d * 64 + ((ks ^ (d & 7) ^ ((d >> 3) & 7)) << 3)]);
          if (dt == 0) accA = __builtin_amdgcn_mfma_f32_32x32x16_bf16(pu.v, vf, accA, 0, 0, 0);
          else         accB = __builtin_amdgcn_mfma_f32_32x32x16_bf16(pu.v, vf, accB, 0, 0, 0);
        }
      }
    }

    if (t + 1 < SEQ / 64) {   /* V writes after compute (loads have landed) */
#pragma unroll
      for (int jj = 0; jj < 2; ++jj) {
        const int kr = jj * 32 + srow;
#pragma unroll
        for (int e = 0; e < 8; ++e) {
          const int d = sslot * 8 + e;
          Vts[cur ^ 1][d * 64 + ((((kr >> 3) ^ (d & 7) ^ ((d >> 3) & 7))) << 3) + (kr & 7)] = vr[jj][e];
        }
      }
    }
    __syncthreads();
  }

  /* epilogue: ctx = acc / l, scatter per C/D row map */
  const float linv = 1.f / l_run;
#pragma unroll
  for (int j = 0; j < 16; ++j) {
    const int rq = (j & 3) + 8 * (j >> 2) + 4 * hh;
    const float lj = __shfl(linv, rq);
    const size_t orow = base + (size_t)(q0 + w * 32 + rq) * HDIM;
    O[orow + ql]      = f2bf(accA[j] * lj);
    O[orow + 32 + ql] = f2bf(accB[j] * lj);
  }
}

/* ---- row LayerNorm over 1024, fp32 ---- */
__global__ void ln_kernel(const float* __restrict__ x, const float* __restrict__ g,
                          const float* __restrict__ bb, float* __restrict__ out) {
  const int row = blockIdx.x;
  const int tid = threadIdx.x;
  const f32x4 v = *(const f32x4*)(x + (size_t)row * HDIM + tid * 4);
  float s = v[0] + v[1] + v[2] + v[3];
  float s2 = v[0] * v[0] + v[1] * v[1] + v[2] * v[2] + v[3] * v[3];
#pragma unroll
  for (int o = 1; o < 64; o <<= 1) { s += __shfl_xor(s, o); s2 += __shfl_xor(s2, o); }
  __shared__ float rs[4], rs2[4];
  if ((tid & 63) == 0) { rs[tid >> 6] = s; rs2[tid >> 6] = s2; }
  __syncthreads();
  s = rs[0] + rs[1] + rs[2] + rs[3];
  s2 = rs2[0] + rs2[1] + rs2[2] + rs2[3];
  const float mu = s * (1.f / HDIM);
  const float var = s2 * (1.f / HDIM) - mu * mu;
  const float inv = rsqrtf(var + 1e-5f);
  f32x4 o4;
#pragma unroll
  for (int e = 0; e < 4; ++e) {
    const int c = tid * 4 + e;
    o4[e] = (v[e] - mu) * inv * g[c] + bb[c];
  }
  *(f32x4*)(out + (size_t)row * HDIM + tid * 4) = o4;
}

extern "C" void kernel_launch(void* const* d_in, const int* in_sizes, int n_in,
                              void* d_out, int out_size, void* d_ws, size_t ws_size,
                              hipStream_t stream) {
  const float* hidden = (const float*)d_in[0];
  const float* topic  = (const float*)d_in[1];
  const float* mask   = (const float*)d_in[2];
  const float* Wq  = (const float*)d_in[3];  const float* bq  = (const float*)d_in[4];
  const float* Wk  = (const float*)d_in[5];  const float* bk  = (const float*)d_in[6];
  const float* Wv  = (const float*)d_in[7];  const float* bv  = (const float*)d_in[8];
  const float* Wtp = (const float*)d_in[9];  const float* btp = (const float*)d_in[10];
  const float* Wta = (const float*)d_in[11]; const float* bta = (const float*)d_in[12];
  const float* Wd  = (const float*)d_in[13]; const float* bd  = (const float*)d_in[14];
  const float* lng = (const float*)d_in[15]; const float* lnb = (const float*)d_in[16];
  float* out = (float*)d_out;

  char* ws = (char*)d_ws;
  u16* hs_bf  = (u16*)(ws);                                  /* 8 MB  */
  u16* WtAll  = (u16*)(ws + (size_t)(8u << 20));             /* 8 MB: q,k,v,d */
  u16* qkv    = (u16*)(ws + (size_t)(16u << 20));            /* 24 MB */
  u16* ctx    = (u16*)(ws + (size_t)(40u << 20));            /* 8 MB  */
  float* xbuf = (float*)(ws + (size_t)(16u << 20));          /* aliases q,k after attn */
  float* tproj = (float*)(ws + (size_t)(48u << 20));
  float* tgate = (float*)(ws + (size_t)(48u << 20) + 8192);
  float* mask2 = (float*)(ws + (size_t)(48u << 20));         /* aliases tproj+tgate (dead by then) */
  float* tpart = (float*)(ws + (size_t)(16u << 20));         /* 128 KB; dead before gemm<0> writes qkv */

  wt_bf16_kernel<<<dim3(32, 32, 4), dim3(32, 8), 0, stream>>>(Wq, Wk, Wv, Wd, WtAll);
  cvt_bf16_kernel<<<4096, 256, 0, stream>>>(hidden, hs_bf);
  topic_partial_kernel<<<dim3(TOPC, NB), 256, 0, stream>>>(topic, Wtp, tpart);
  topic_reduce_kernel<<<dim3(4, NB), 256, 0, stream>>>(tpart, btp, tproj, 0);
  topic_partial_kernel<<<dim3(TOPC, NB), 256, 0, stream>>>(tproj, Wta, tpart);
  topic_reduce_kernel<<<dim3(4, NB), 256, 0, stream>>>(tpart, bta, tgate, 1);
  gemm_kernel<0><<<dim3(8, 32, 3), 256, 0, stream>>>(hs_bf, WtAll, bq, bk, bv, tgate,
                                                     nullptr, qkv, nullptr);
  maskcvt_kernel<<<16, 256, 0, stream>>>(mask, mask2);
  attn_kernel<<<dim3(16, 16, NB), 256, 0, stream>>>(qkv, qkv + (size_t)MROWS * HDIM,
                                                    qkv + 2 * (size_t)MROWS * HDIM, mask2, ctx);
  gemm_kernel<1><<<dim3(8, 32, 1), 256, 0, stream>>>(ctx, WtAll + 3 * (size_t)HDIM * HDIM,
                                                     bd, nullptr, nullptr, nullptr, hidden,
                                                     nullptr, xbuf);
  ln_kernel<<<4096, 256, 0, stream>>>(xbuf, lng, lnb, out);
}